// Round 14
// baseline (2306.260 us; speedup 1.0000x reference)
//
#include <hip/hip_runtime.h>

#define S 512
#define B 256
#define D 128
#define H1 128
#define H2 256

#define NWG 80

// byte offsets in ws
#define OFF_XPROJ 0u          // [B][512] f32 = 524288
#define OFF_H1C   524288u     // [4][B][32] 16B chunks (hi|lo) = 524288
#define OFF_H2C   1048576u    // [4][B][64] 16B chunks = 1048576
#define OFF_OUTP  2097152u    // [S][8][B] f32 = 4194304
#define OFF_FLAG  6291456u    // 8 grp * 64 int (agent scope): slot = s*32 + role

#define DYN_LDS 33792

typedef unsigned long long ull;
typedef unsigned short ushort;
typedef unsigned int uint;
typedef __attribute__((ext_vector_type(8))) short short8;
typedef __attribute__((ext_vector_type(4))) float f32x4;
typedef __attribute__((ext_vector_type(4))) uint u32x4;

__device__ __forceinline__ ushort f2bf(float f){
  unsigned u = __float_as_uint(f);
  unsigned r = u + 0x7fffu + ((u>>16)&1u);
  return (ushort)(r>>16);
}
__device__ __forceinline__ float rcpf_(float x){ return __builtin_amdgcn_rcpf(x); }
__device__ __forceinline__ float sigm(float x){ return rcpf_(1.f + __expf(-x)); }
__device__ __forceinline__ float tanh_(float x){ return 1.f - 2.f*rcpf_(1.f + __expf(2.f*x)); }

__device__ __forceinline__ int aldi(const int* p){
  return __hip_atomic_load(p, __ATOMIC_RELAXED, __HIP_MEMORY_SCOPE_AGENT);
}
__device__ __forceinline__ void asti(int* p, int v){
  __hip_atomic_store(p, v, __ATOMIC_RELAXED, __HIP_MEMORY_SCOPE_AGENT);
}
__device__ __forceinline__ u32x4 ld16(const u32x4* p){
  u32x4 v;
  asm volatile("global_load_dwordx4 %0, %1, off sc0 sc1"
               : "=v"(v) : "v"((ull)(size_t)p));
  return v;
}
__device__ __forceinline__ void st16(u32x4* p, u32x4 v){
  asm volatile("global_store_dwordx4 %0, %1, off sc0 sc1"
               :: "v"((ull)(size_t)p), "v"(v) : "memory");
}
__device__ __forceinline__ void drain_vm(){
  asm volatile("s_waitcnt vmcnt(0)" ::: "memory");
  __builtin_amdgcn_sched_barrier(0);
}
__device__ __forceinline__ void wait_vm6(){
  asm volatile("s_waitcnt vmcnt(6)" ::: "memory");
  __builtin_amdgcn_sched_barrier(0);
}
__device__ __forceinline__ void wait_vm2(){
  asm volatile("s_waitcnt vmcnt(2)" ::: "memory");
  __builtin_amdgcn_sched_barrier(0);
}
__device__ __forceinline__ ull lo64(u32x4 v){ return ((ull)v.y<<32) | v.x; }
__device__ __forceinline__ ull hi64(u32x4 v){ return ((ull)v.w<<32) | v.z; }

// ---------------- init kernels ----------------
__global__ void k_zero(char* wsb){
  long long id = (long long)blockIdx.x*blockDim.x + threadIdx.x;
  long long stride = (long long)gridDim.x*blockDim.x;
  ull* h = (ull*)(wsb + OFF_H1C);      // h1c + h2c contiguous = 1572864 B
  for (long long i = id; i < 196608; i += stride) h[i] = 0ull;
  ull* f = (ull*)(wsb + OFF_FLAG);     // 2048 B flags
  for (long long i = id; i < 256; i += stride) f[i] = 0ull;
}

__global__ void k_xproj(const float* __restrict__ x, const float* __restrict__ Wih1,
                        const float* __restrict__ bih1, const float* __restrict__ bhh1,
                        char* __restrict__ wsb){
  __shared__ float xs[D];
  float* xproj = (float*)(wsb + OFF_XPROJ);
  int b = blockIdx.x;
  for (int d = threadIdx.x; d < D; d += blockDim.x) xs[d] = x[b*D + d];
  __syncthreads();
  for (int g = threadIdx.x; g < 4*H1; g += blockDim.x){
    float acc = bih1[g] + bhh1[g];
    const float* w = &Wih1[(size_t)g*D];
    #pragma unroll 8
    for (int d = 0; d < D; ++d) acc += xs[d]*w[d];
    xproj[(size_t)b*512 + g] = acc;
  }
}

// ---------------- persistent kernel ----------------
__global__ void __launch_bounds__(256,1)
k_persist(const float* __restrict__ Whh1,
          const float* __restrict__ Wih2, const float* __restrict__ Whh2,
          const float* __restrict__ bih2, const float* __restrict__ bhh2,
          const float* __restrict__ Wout,
          char* __restrict__ wsb){
  extern __shared__ char sm[];
  const int wg = blockIdx.x;
  const int t  = threadIdx.x;
  const int grp = wg & 7, role = wg >> 3;     // XCD-local groups
  const int gb0 = grp * 32;
  const int l = t & 63, wv = t >> 6, lr = l & 15, lk = (l >> 4) * 8;

  float* xproj = (float*)(wsb + OFF_XPROJ);
  u32x4* h1c = (u32x4*)(wsb + OFF_H1C);   // [4][B][32] chunks
  u32x4* h2c = (u32x4*)(wsb + OFF_H2C);   // [4][B][64] chunks
  float* outp = (float*)(wsb + OFF_OUTP);
  int* gf = (int*)(wsb + OFF_FLAG) + grp*64;   // slot = s*32 + role

  int bud = 1<<21;

  if (role < 2){
    // ======= layer-1 WG: 64 units, 2 streams x 16 batches =======
    const int u0 = role * 64;
    ushort* hsH = (ushort*)sm;            // [16][136]
    ushort* hsL = (ushort*)(sm + 4352);
    float*  gl  = (float*)(sm + 8704);    // [16][260]
    short8 bhi[4][4], blo[4][4];
    #pragma unroll
    for (int kt=0;kt<4;++kt){
      #pragma unroll
      for (int ct=0;ct<4;++ct){
        int col = wv*64 + ct*16 + lr;
        int lu = col>>2, g = col&3;
        const float* src = Whh1 + (size_t)(g*H1 + u0 + lu)*D + kt*32 + lk;
        short8 vh, vl;
        #pragma unroll
        for (int j=0;j<8;++j){
          float w = src[j];
          ushort hbv = f2bf(w);
          float hf = __uint_as_float((unsigned)hbv<<16);
          vh[j] = (short)hbv; vl[j] = (short)f2bf(w - hf);
        }
        bhi[kt][ct]=vh; blo[kt][ct]=vl;
      }
    }
    f32x4 xpfA[4], xpfB[4];
    #pragma unroll
    for (int ct=0;ct<4;++ct){
      int col = wv*64 + ct*16 + lr;
      int lu = col>>2, g = col&3;
      #pragma unroll
      for (int q=0;q<4;++q){
        int row = (l>>4)*4 + q;
        xpfA[ct][q] = xproj[(size_t)(gb0 + row)*512 + g*H1 + u0 + lu];
        xpfB[ct][q] = xproj[(size_t)(gb0 + 16 + row)*512 + g*H1 + u0 + lu];
      }
    }
    float c1A[4] = {0,0,0,0}, c1B[4] = {0,0,0,0};
    int lastfA = (t<10)?0:0x7fffffff, lastfB = (t<10)?0:0x7fffffff;
    u32x4 tvA[2], tvB[2];

    auto P1 = [&](int sbase, int fbase, int& lastf_, int r, u32x4 (&tv)[2]){
      if (r > 0 && t < 64){
        int need = (t<2) ? r : (r-2);
        if (!__all((t<10) ? (lastf_>=need) : true)){
          for(;;){
            if (t<10) lastf_ = aldi(&gf[fbase + t]);
            if (__all((t<10) ? (lastf_>=need) : true)) break;
            if (--bud < 0) break;
            __builtin_amdgcn_s_sleep(1);
          }
        }
      }
      __syncthreads();
      const u32x4* sB = h1c + (size_t)((r-1)&3)*8192;
      #pragma unroll
      for (int m=0;m<2;++m){
        int id = t + m*256;
        tv[m] = ld16(&sB[(size_t)(sbase + (id>>5))*32 + (id&31)]);
      }
    };
    auto P2 = [&](int sbase, int fbase, int r, u32x4 (&tv)[2],
                  float (&c1s)[4], f32x4 (&xpfS)[4], bool head){
      if (head) wait_vm2();
      #pragma unroll
      for (int m=0;m<2;++m){
        int id = t + m*256;
        int row = id>>5, c = id&31;
        *(ull*)(hsH + row*136 + c*4) = lo64(tv[m]);
        *(ull*)(hsL + row*136 + c*4) = hi64(tv[m]);
      }
      __syncthreads();
      f32x4 acc[4];
      #pragma unroll
      for (int ct=0;ct<4;++ct) acc[ct] = xpfS[ct];
      #pragma unroll
      for (int kt=0;kt<4;++kt){
        int off = lr*136 + kt*32 + lk;
        short8 ah = *(const short8*)(hsH + off);
        short8 al = *(const short8*)(hsL + off);
        #pragma unroll
        for (int ct=0;ct<4;++ct){
          acc[ct] = __builtin_amdgcn_mfma_f32_16x16x32_bf16(ah, bhi[kt][ct], acc[ct],0,0,0);
          acc[ct] = __builtin_amdgcn_mfma_f32_16x16x32_bf16(al, bhi[kt][ct], acc[ct],0,0,0);
          acc[ct] = __builtin_amdgcn_mfma_f32_16x16x32_bf16(ah, blo[kt][ct], acc[ct],0,0,0);
        }
      }
      #pragma unroll
      for (int ct=0;ct<4;++ct){
        #pragma unroll
        for (int q=0;q<4;++q)
          gl[((l>>4)*4 + q)*260 + wv*64 + ct*16 + lr] = acc[ct][q];
      }
      __syncthreads();
      const int nb = t>>4, lu0 = (t&15)*4;
      ushort hb[4], lb[4];
      #pragma unroll
      for (int j=0;j<4;++j){
        f32x4 gv = *(const f32x4*)&gl[nb*260 + (lu0+j)*4];
        float ig = sigm(gv[0]), fg = sigm(gv[1]);
        float gg = tanh_(gv[2]), og = sigm(gv[3]);
        c1s[j] = fg*c1s[j] + ig*gg;
        float h = og*tanh_(c1s[j]);
        hb[j] = f2bf(h);
        lb[j] = f2bf(h - __uint_as_float((unsigned)hb[j]<<16));
      }
      u32x4 v0;
      v0.x = (uint)hb[0] | ((uint)hb[1]<<16); v0.y = (uint)hb[2] | ((uint)hb[3]<<16);
      v0.z = (uint)lb[0] | ((uint)lb[1]<<16); v0.w = (uint)lb[2] | ((uint)lb[3]<<16);
      st16(&h1c[(size_t)(r&3)*8192 + (size_t)(sbase + nb)*32 + (u0>>2) + (t&15)], v0);
      drain_vm();
      __syncthreads();
      if (t == 0) asti(&gf[fbase + role], r+1);
    };

    P1(gb0, 0, lastfA, 0, tvA);
    drain_vm();
    for (int r=0; r<S; ++r){
      P1(gb0+16, 32, lastfB, r, tvB);
      P2(gb0,    0,  r, tvA, c1A, xpfA, true);
      P2(gb0+16, 32, r, tvB, c1B, xpfB, false);
      if (r+1 < S) P1(gb0, 0, lastfA, r+1, tvA);
    }
  } else {
    // ======= layer-2 WG: 32 units, 2 streams x 16 batches =======
    const int us = role - 2;
    const int u0 = us * 32;
    ushort* hcH = (ushort*)sm;             // [16][392]
    ushort* hcL = (ushort*)(sm + 12544);
    float*  gl  = (float*)(sm + 25088);    // [16][132]
    short8 bhi[12][2], blo[12][2];
    #pragma unroll
    for (int kt=0;kt<12;++kt){
      #pragma unroll
      for (int ct=0;ct<2;++ct){
        int col = wv*32 + ct*16 + lr;
        int lu = col>>2, g = col&3;
        int row = g*H2 + u0 + lu;
        const float* src = (kt<4) ? (Wih2 + (size_t)row*D + kt*32 + lk)
                                  : (Whh2 + (size_t)row*H2 + (kt-4)*32 + lk);
        short8 vh, vl;
        #pragma unroll
        for (int j=0;j<8;++j){
          float w = src[j];
          ushort hbv = f2bf(w);
          float hf = __uint_as_float((unsigned)hbv<<16);
          vh[j] = (short)hbv; vl[j] = (short)f2bf(w - hf);
        }
        bhi[kt][ct]=vh; blo[kt][ct]=vl;
      }
    }
    float biasv[2];
    #pragma unroll
    for (int ct=0;ct<2;++ct){
      int col = wv*32 + ct*16 + lr;
      int lu = col>>2, g = col&3;
      biasv[ct] = bih2[g*H2+u0+lu] + bhh2[g*H2+u0+lu];
    }
    const int p = t & 15;
    const float wo0 = Wout[u0 + 2*p], wo1 = Wout[u0 + 2*p + 1];
    float c2A[2] = {0,0}, c2B[2] = {0,0};
    int lastfA = (t<10)?0:0x7fffffff, lastfB = (t<10)?0:0x7fffffff;
    u32x4 t1A[2], t2A[4], t1B[2], t2B[4];

    auto P1 = [&](int sbase, int fbase, int& lastf_, int rr,
                  u32x4 (&t1)[2], u32x4 (&t2)[4]){
      if (t < 64){
        if (!__all((t<10) ? (lastf_>=rr) : true)){
          for(;;){
            if (t<10) lastf_ = aldi(&gf[fbase + t]);
            if (__all((t<10) ? (lastf_>=rr) : true)) break;
            if (--bud < 0) break;
            __builtin_amdgcn_s_sleep(1);
          }
        }
      }
      __syncthreads();
      const u32x4* s1 = h1c + (size_t)((rr-1)&3)*8192;
      #pragma unroll
      for (int m=0;m<2;++m){
        int id = t + m*256;
        t1[m] = ld16(&s1[(size_t)(sbase + (id>>5))*32 + (id&31)]);
      }
      const u32x4* s2 = h2c + (size_t)((rr-2)&3)*16384;
      #pragma unroll
      for (int m=0;m<4;++m){
        int id = t + m*256;
        t2[m] = ld16(&s2[(size_t)(sbase + (id>>6))*64 + (id&63)]);
      }
    };
    auto P2 = [&](int sbase, int fbase, int rr, u32x4 (&t1)[2], u32x4 (&t2)[4],
                  float (&c2s)[2], bool head){
      if (head) wait_vm6();
      #pragma unroll
      for (int m=0;m<2;++m){
        int id = t + m*256;
        int row = id>>5, c = id&31;
        *(ull*)(hcH + row*392 + c*4) = lo64(t1[m]);
        *(ull*)(hcL + row*392 + c*4) = hi64(t1[m]);
      }
      #pragma unroll
      for (int m=0;m<4;++m){
        int id = t + m*256;
        int row = id>>6, c = id&63;
        *(ull*)(hcH + row*392 + 128 + c*4) = lo64(t2[m]);
        *(ull*)(hcL + row*392 + 128 + c*4) = hi64(t2[m]);
      }
      __syncthreads();
      f32x4 acc[2];
      #pragma unroll
      for (int ct=0;ct<2;++ct){
        f32x4 a; a[0]=biasv[ct]; a[1]=biasv[ct]; a[2]=biasv[ct]; a[3]=biasv[ct];
        acc[ct]=a;
      }
      #pragma unroll
      for (int kt=0;kt<12;++kt){
        int off = lr*392 + kt*32 + lk;
        short8 ah = *(const short8*)(hcH + off);
        short8 al = *(const short8*)(hcL + off);
        #pragma unroll
        for (int ct=0;ct<2;++ct){
          acc[ct] = __builtin_amdgcn_mfma_f32_16x16x32_bf16(ah, bhi[kt][ct], acc[ct],0,0,0);
          acc[ct] = __builtin_amdgcn_mfma_f32_16x16x32_bf16(al, bhi[kt][ct], acc[ct],0,0,0);
          acc[ct] = __builtin_amdgcn_mfma_f32_16x16x32_bf16(ah, blo[kt][ct], acc[ct],0,0,0);
        }
      }
      #pragma unroll
      for (int ct=0;ct<2;++ct){
        #pragma unroll
        for (int q=0;q<4;++q)
          gl[((l>>4)*4 + q)*132 + wv*32 + ct*16 + lr] = acc[ct][q];
      }
      __syncthreads();
      const int nb = t>>4;
      float psum;
      uint myhi, mylo;
      {
        f32x4 g0 = *(const f32x4*)&gl[nb*132 + (2*p)*4];
        f32x4 g1 = *(const f32x4*)&gl[nb*132 + (2*p+1)*4];
        float i0 = sigm(g0[0]), f0 = sigm(g0[1]), gg0 = tanh_(g0[2]), o0 = sigm(g0[3]);
        c2s[0] = f0*c2s[0] + i0*gg0;
        float h0 = o0*tanh_(c2s[0]);
        float i1 = sigm(g1[0]), f1 = sigm(g1[1]), gg1 = tanh_(g1[2]), o1 = sigm(g1[3]);
        c2s[1] = f1*c2s[1] + i1*gg1;
        float h1v = o1*tanh_(c2s[1]);
        psum = h0*wo0 + h1v*wo1;
        ushort hb0 = f2bf(h0), hb1 = f2bf(h1v);
        ushort lb0 = f2bf(h0 - __uint_as_float((unsigned)hb0<<16));
        ushort lb1 = f2bf(h1v - __uint_as_float((unsigned)hb1<<16));
        myhi = (uint)hb0 | ((uint)hb1<<16);
        mylo = (uint)lb0 | ((uint)lb1<<16);
      }
      uint othhi = (uint)__shfl_xor((int)myhi, 1, 64);
      uint othlo = (uint)__shfl_xor((int)mylo, 1, 64);
      if ((t & 1) == 0){
        u32x4 v; v.x = myhi; v.y = othhi; v.z = mylo; v.w = othlo;
        st16(&h2c[(size_t)((rr-1)&3)*16384 + (size_t)(sbase + nb)*64 + (u0>>2) + (p>>1)], v);
      }
      drain_vm();
      __syncthreads();
      if (t == 0) asti(&gf[fbase + role], rr+1);
      psum += __shfl_xor(psum, 1, 64);
      psum += __shfl_xor(psum, 2, 64);
      psum += __shfl_xor(psum, 4, 64);
      psum += __shfl_xor(psum, 8, 64);
      if (p == 0) outp[(size_t)(rr-1)*2048 + us*256 + sbase + nb] = psum;
    };

    __syncthreads();
    if (t == 0){ asti(&gf[role], 1); asti(&gf[32 + role], 1); }
    P1(gb0, 0, lastfA, 1, t1A, t2A);
    drain_vm();
    for (int rr=1; rr<=S; ++rr){
      P1(gb0+16, 32, lastfB, rr, t1B, t2B);
      P2(gb0,    0,  rr, t1A, t2A, c2A, true);
      P2(gb0+16, 32, rr, t1B, t2B, c2B, false);
      if (rr < S) P1(gb0, 0, lastfA, rr+1, t1A, t2A);
    }
  }
}

__global__ void k_final(const char* __restrict__ wsb, const float* __restrict__ bout,
                        float* __restrict__ out){
  const float* outp = (const float*)(wsb + OFF_OUTP);
  int id = blockIdx.x*blockDim.x + threadIdx.x;
  if (id >= B*S) return;
  int tt = id >> 8;
  int b  = id & 255;
  float s = bout[0];
  const float* p = outp + (size_t)tt*2048 + b;
  #pragma unroll
  for (int u = 0; u < 8; ++u) s += p[(size_t)u*256];
  out[(size_t)b*S + tt] = s;
}

extern "C" void kernel_launch(void* const* d_in, const int* in_sizes, int n_in,
                              void* d_out, int out_size, void* d_ws, size_t ws_size,
                              hipStream_t stream){
  const float* x    = (const float*)d_in[0];
  const float* Wih1 = (const float*)d_in[1];
  const float* Whh1 = (const float*)d_in[2];
  const float* bih1 = (const float*)d_in[3];
  const float* bhh1 = (const float*)d_in[4];
  const float* Wih2 = (const float*)d_in[5];
  const float* Whh2 = (const float*)d_in[6];
  const float* bih2 = (const float*)d_in[7];
  const float* bhh2 = (const float*)d_in[8];
  const float* Wout = (const float*)d_in[9];
  const float* bout = (const float*)d_in[10];
  char* wsb  = (char*)d_ws;
  float* out = (float*)d_out;

  (void)hipFuncSetAttribute((const void*)k_persist,
                            hipFuncAttributeMaxDynamicSharedMemorySize, DYN_LDS);

  k_zero<<<dim3(64), dim3(256), 0, stream>>>(wsb);
  k_xproj<<<dim3(B), dim3(256), 0, stream>>>(x, Wih1, bih1, bhh1, wsb);
  k_persist<<<dim3(NWG), dim3(256), DYN_LDS, stream>>>(Whh1, Wih2, Whh2, bih2, bhh2, Wout, wsb);
  k_final<<<dim3((B*S)/256), dim3(256), 0, stream>>>(wsb, bout, out);
}

// Round 15
// 2017.925 us; speedup vs baseline: 1.1429x; 1.1429x over previous
//
#include <hip/hip_runtime.h>

#define S 512
#define B 256
#define D 128
#define H1 128
#define H2 256

#define NWG 80

// byte offsets in ws
#define OFF_XPROJ 0u          // [B][512] f32 = 524288
#define OFF_H1C   524288u     // [4][B][32] 16B chunks (hi|lo) = 524288
#define OFF_H2C   1048576u    // [4][B][64] 16B chunks = 1048576
#define OFF_OUTP  2097152u    // [S][8][B] f32 = 4194304
#define OFF_FLAG  6291456u    // 8 grp * 32 int (agent scope, write-safety only)

#define DYN_LDS 67072

typedef unsigned long long ull;
typedef unsigned short ushort;
typedef unsigned int uint;
typedef __attribute__((ext_vector_type(8))) short short8;
typedef __attribute__((ext_vector_type(4))) float f32x4;
typedef __attribute__((ext_vector_type(4))) uint u32x4;

__device__ __forceinline__ ushort f2bf(float f){
  unsigned u = __float_as_uint(f);
  unsigned r = u + 0x7fffu + ((u>>16)&1u);
  return (ushort)(r>>16);
}
__device__ __forceinline__ float rcpf_(float x){ return __builtin_amdgcn_rcpf(x); }
__device__ __forceinline__ float sigm(float x){ return rcpf_(1.f + __expf(-x)); }
__device__ __forceinline__ float tanh_(float x){ return 1.f - 2.f*rcpf_(1.f + __expf(2.f*x)); }

__device__ __forceinline__ int aldi(const int* p){
  return __hip_atomic_load(p, __ATOMIC_RELAXED, __HIP_MEMORY_SCOPE_AGENT);
}
__device__ __forceinline__ void asti(int* p, int v){
  __hip_atomic_store(p, v, __ATOMIC_RELAXED, __HIP_MEMORY_SCOPE_AGENT);
}
__device__ __forceinline__ u32x4 ld16(const u32x4* p){
  u32x4 v;
  asm volatile("global_load_dwordx4 %0, %1, off sc0 sc1"
               : "=v"(v) : "v"((ull)(size_t)p));
  return v;
}
__device__ __forceinline__ void st16(u32x4* p, u32x4 v){
  asm volatile("global_store_dwordx4 %0, %1, off sc0 sc1"
               :: "v"((ull)(size_t)p), "v"(v) : "memory");
}
__device__ __forceinline__ void drain_vm(){
  asm volatile("s_waitcnt vmcnt(0)" ::: "memory");
  __builtin_amdgcn_sched_barrier(0);
}
__device__ __forceinline__ ull lo64(u32x4 v){ return ((ull)v.y<<32) | v.x; }
__device__ __forceinline__ ull hi64(u32x4 v){ return ((ull)v.w<<32) | v.z; }
// 4-bit round tag lives in LSBs of the 4 bf16-lo halves (.z, .w)
__device__ __forceinline__ bool tag_ok(u32x4 v, int tg){
  int got = (v.z & 1) | (((v.z>>16)&1)<<1) | ((v.w&1)<<2) | (((v.w>>16)&1)<<3);
  return got == tg;
}

// ---------------- init kernels ----------------
__global__ void k_zero(char* wsb){
  long long id = (long long)blockIdx.x*blockDim.x + threadIdx.x;
  long long stride = (long long)gridDim.x*blockDim.x;
  u32x4* h = (u32x4*)(wsb + OFF_H1C);   // h1c (32768) + h2c (65536) chunks
  u32x4 z; z.x = 0u; z.y = 0u; z.z = 0x00010001u; z.w = 0x00010001u;  // zeros, tag 15
  for (long long i = id; i < 98304; i += stride) h[i] = z;
  ull* f = (ull*)(wsb + OFF_FLAG);
  for (long long i = id; i < 128; i += stride) f[i] = 0ull;
}

__global__ void k_xproj(const float* __restrict__ x, const float* __restrict__ Wih1,
                        const float* __restrict__ bih1, const float* __restrict__ bhh1,
                        char* __restrict__ wsb){
  __shared__ float xs[D];
  float* xproj = (float*)(wsb + OFF_XPROJ);
  int b = blockIdx.x;
  for (int d = threadIdx.x; d < D; d += blockDim.x) xs[d] = x[b*D + d];
  __syncthreads();
  for (int g = threadIdx.x; g < 4*H1; g += blockDim.x){
    float acc = bih1[g] + bhh1[g];
    const float* w = &Wih1[(size_t)g*D];
    #pragma unroll 8
    for (int d = 0; d < D; ++d) acc += xs[d]*w[d];
    xproj[(size_t)b*512 + g] = acc;
  }
}

// ---------------- persistent kernel ----------------
__global__ void __launch_bounds__(256,1)
k_persist(const float* __restrict__ Whh1,
          const float* __restrict__ Wih2, const float* __restrict__ Whh2,
          const float* __restrict__ bih2, const float* __restrict__ bhh2,
          const float* __restrict__ Wout,
          char* __restrict__ wsb){
  extern __shared__ char sm[];
  const int wg = blockIdx.x;
  const int t  = threadIdx.x;
  const int grp = wg & 7, role = wg >> 3;     // XCD-local groups
  const int gb0 = grp * 32;
  const int l = t & 63, wv = t >> 6, lr = l & 15, lk = (l >> 4) * 8;

  float* xproj = (float*)(wsb + OFF_XPROJ);
  u32x4* h1c = (u32x4*)(wsb + OFF_H1C);   // [4][B][32] chunks; 8192/slot
  u32x4* h2c = (u32x4*)(wsb + OFF_H2C);   // [4][B][64] chunks; 16384/slot
  float* outp = (float*)(wsb + OFF_OUTP);
  int* gf = (int*)(wsb + OFF_FLAG) + grp*32;
  int bud = 1<<20;

  if (role < 2){
    // ======= layer-1 WG: 64 units, 32 batches; tag-verified self-recurrence =======
    const int u0 = role * 64;
    ushort* hsH = (ushort*)sm;            // [32][136]
    ushort* hsL = (ushort*)(sm + 8704);
    float*  gl  = (float*)(sm + 17408);   // [32][260]
    short8 bhi[4][4], blo[4][4];
    #pragma unroll
    for (int kt=0;kt<4;++kt){
      #pragma unroll
      for (int ct=0;ct<4;++ct){
        int col = wv*64 + ct*16 + lr;
        int lu = col>>2, g = col&3;
        const float* src = Whh1 + (size_t)(g*H1 + u0 + lu)*D + kt*32 + lk;
        short8 vh, vl;
        #pragma unroll
        for (int j=0;j<8;++j){
          float w = src[j];
          ushort hbv = f2bf(w);
          float hf = __uint_as_float((unsigned)hbv<<16);
          vh[j] = (short)hbv; vl[j] = (short)f2bf(w - hf);
        }
        bhi[kt][ct]=vh; blo[kt][ct]=vl;
      }
    }
    f32x4 xpf[2][4];
    #pragma unroll
    for (int bt=0;bt<2;++bt){
      #pragma unroll
      for (int ct=0;ct<4;++ct){
        int col = wv*64 + ct*16 + lr;
        int lu = col>>2, g = col&3;
        #pragma unroll
        for (int q=0;q<4;++q){
          int b = gb0 + bt*16 + (l>>4)*4 + q;
          xpf[bt][ct][q] = xproj[(size_t)b*512 + g*H1 + u0 + lu];
        }
      }
    }
    const int nb = t>>3, lu0 = (t&7)*8;
    float c1[8] = {0.f,0.f,0.f,0.f,0.f,0.f,0.f,0.f};
    int lastf = (t<10) ? 0 : 0x7fffffff;

    for (int r=0; r<S; ++r){
      // speculative loads of h1[r-1]
      const u32x4* sB = h1c + (size_t)((r-1)&3)*8192;
      u32x4 tv[4];
      #pragma unroll
      for (int m=0;m<4;++m){
        int id = t + m*256;
        tv[m] = ld16(&sB[(size_t)(gb0 + (id>>5))*32 + (id&31)]);
      }
      // lagged write-safety: all 10 flags >= r-2 (cached; poll rarely)
      if (t < 64){
        int need = r-2;
        if (!__all((t<10) ? (lastf>=need) : true)){
          for(;;){
            if (t<10) lastf = aldi(&gf[t]);
            if (__all((t<10) ? (lastf>=need) : true)) break;
            if (--bud < 0) break;
            __builtin_amdgcn_s_sleep(1);
          }
        }
      }
      drain_vm();
      // tag-verify + retry
      {
        int tg = (r-1)&15;
        for(;;){
          bool ok = tag_ok(tv[0],tg) && tag_ok(tv[1],tg) && tag_ok(tv[2],tg) && tag_ok(tv[3],tg);
          if (ok) break;
          if (--bud < 0) break;
          #pragma unroll
          for (int m=0;m<4;++m){
            if (!tag_ok(tv[m],tg)){
              int id = t + m*256;
              tv[m] = ld16(&sB[(size_t)(gb0 + (id>>5))*32 + (id&31)]);
            }
          }
          drain_vm();
        }
      }
      #pragma unroll
      for (int m=0;m<4;++m){
        int id = t + m*256;
        int b = id>>5, c = id&31;
        *(ull*)(hsH + b*136 + c*4) = lo64(tv[m]);
        *(ull*)(hsL + b*136 + c*4) = hi64(tv[m]);
      }
      __syncthreads();
      f32x4 acc[2][4];
      #pragma unroll
      for (int bt=0;bt<2;++bt){
        #pragma unroll
        for (int ct=0;ct<4;++ct) acc[bt][ct]=xpf[bt][ct];
      }
      #pragma unroll
      for (int kt=0;kt<4;++kt){
        short8 ah[2], al[2];
        #pragma unroll
        for (int bt=0;bt<2;++bt){
          int off = (bt*16+lr)*136 + kt*32 + lk;
          ah[bt] = *(const short8*)(hsH + off);
          al[bt] = *(const short8*)(hsL + off);
        }
        #pragma unroll
        for (int bt=0;bt<2;++bt){
          #pragma unroll
          for (int ct=0;ct<4;++ct){
            acc[bt][ct] = __builtin_amdgcn_mfma_f32_16x16x32_bf16(ah[bt], bhi[kt][ct], acc[bt][ct],0,0,0);
            acc[bt][ct] = __builtin_amdgcn_mfma_f32_16x16x32_bf16(al[bt], bhi[kt][ct], acc[bt][ct],0,0,0);
            acc[bt][ct] = __builtin_amdgcn_mfma_f32_16x16x32_bf16(ah[bt], blo[kt][ct], acc[bt][ct],0,0,0);
          }
        }
      }
      #pragma unroll
      for (int bt=0;bt<2;++bt){
        #pragma unroll
        for (int ct=0;ct<4;++ct){
          #pragma unroll
          for (int q=0;q<4;++q)
            gl[(bt*16 + (l>>4)*4 + q)*260 + wv*64 + ct*16 + lr] = acc[bt][ct][q];
        }
      }
      __syncthreads();
      float hv[8];
      #pragma unroll
      for (int j=0;j<8;++j){
        f32x4 gv = *(const f32x4*)&gl[nb*260 + (lu0+j)*4];
        float ig = sigm(gv[0]), fg = sigm(gv[1]);
        float gg = tanh_(gv[2]), og = sigm(gv[3]);
        c1[j] = fg*c1[j] + ig*gg;
        hv[j] = og*tanh_(c1[j]);
      }
      ushort hb[8], lb[8];
      #pragma unroll
      for (int j=0;j<8;++j){
        hb[j] = f2bf(hv[j]);
        float hf = __uint_as_float((unsigned)hb[j]<<16);
        lb[j] = f2bf(hv[j]-hf);
      }
      // embed tag r&15 into lo LSBs (both chunks)
      {
        int tg = r & 15;
        #pragma unroll
        for (int j=0;j<8;++j)
          lb[j] = (ushort)((lb[j] & 0xFFFEu) | (uint)((tg>>(j&3))&1));
      }
      size_t db = (size_t)(r&3)*8192 + (size_t)(gb0+nb)*32 + ((u0+lu0)>>2);
      u32x4 v0, v1;
      v0.x = (uint)hb[0] | ((uint)hb[1]<<16); v0.y = (uint)hb[2] | ((uint)hb[3]<<16);
      v0.z = (uint)lb[0] | ((uint)lb[1]<<16); v0.w = (uint)lb[2] | ((uint)lb[3]<<16);
      v1.x = (uint)hb[4] | ((uint)hb[5]<<16); v1.y = (uint)hb[6] | ((uint)hb[7]<<16);
      v1.z = (uint)lb[4] | ((uint)lb[5]<<16); v1.w = (uint)lb[6] | ((uint)lb[7]<<16);
      st16(&h1c[db],   v0);
      st16(&h1c[db+1], v1);
      // publish round counter (write-safety only; NO drain needed)
      __syncthreads();
      if (t == 0) asti(&gf[role], r+1);
    }
  } else {
    // ======= layer-2 WG: 32 units, 32 batches; tag-verified exchange =======
    const int us = role - 2;
    const int u0 = us * 32;
    ushort* hcH = (ushort*)sm;             // [32][392]
    ushort* hcL = (ushort*)(sm + 25088);
    float*  gl  = (float*)(sm + 50176);    // [32][132]
    short8 bhi[12][2], blo[12][2];
    #pragma unroll
    for (int kt=0;kt<12;++kt){
      #pragma unroll
      for (int ct=0;ct<2;++ct){
        int col = wv*32 + ct*16 + lr;
        int lu = col>>2, g = col&3;
        int row = g*H2 + u0 + lu;
        const float* src = (kt<4) ? (Wih2 + (size_t)row*D + kt*32 + lk)
                                  : (Whh2 + (size_t)row*H2 + (kt-4)*32 + lk);
        short8 vh, vl;
        #pragma unroll
        for (int j=0;j<8;++j){
          float w = src[j];
          ushort hbv = f2bf(w);
          float hf = __uint_as_float((unsigned)hbv<<16);
          vh[j] = (short)hbv; vl[j] = (short)f2bf(w - hf);
        }
        bhi[kt][ct]=vh; blo[kt][ct]=vl;
      }
    }
    float biasv[2];
    #pragma unroll
    for (int ct=0;ct<2;++ct){
      int col = wv*32 + ct*16 + lr;
      int lu = col>>2, g = col&3;
      biasv[ct] = bih2[g*H2+u0+lu] + bhh2[g*H2+u0+lu];
    }
    const int nb = t>>3, lu0 = (t&7)*4;
    float wo[4];
    #pragma unroll
    for (int j=0;j<4;++j) wo[j] = Wout[u0+lu0+j];
    float c2[4] = {0.f,0.f,0.f,0.f};
    int lastf = (t<10) ? 0 : 0x7fffffff;

    __syncthreads();
    if (t == 0) asti(&gf[role], 1);

    for (int rr=1; rr<=S; ++rr){
      const int ts = rr-1;
      const u32x4* s1 = h1c + (size_t)((rr-1)&3)*8192;
      const u32x4* s2 = h2c + (size_t)((rr-2)&3)*16384;
      // ---- speculative loads at round top (h1 + h2, one overlapped batch) ----
      u32x4 t1[4], t2[8];
      #pragma unroll
      for (int m=0;m<4;++m){
        int id = t + m*256;
        t1[m] = ld16(&s1[(size_t)(gb0 + (id>>5))*32 + (id&31)]);
      }
      #pragma unroll
      for (int m=0;m<8;++m){
        int id = t + m*256;
        t2[m] = ld16(&s2[(size_t)(gb0 + (id>>6))*64 + (id&63)]);
      }
      // ---- lagged write-safety: all 10 flags >= rr-2 (cached) ----
      if (t < 64){
        int need = rr-2;
        if (!__all((t<10) ? (lastf>=need) : true)){
          for(;;){
            if (t<10) lastf = aldi(&gf[t]);
            if (__all((t<10) ? (lastf>=need) : true)) break;
            if (--bud < 0) break;
            __builtin_amdgcn_s_sleep(1);
          }
        }
      }
      drain_vm();
      // ---- verify h1 tags ----
      {
        int tg = (rr-1)&15;
        for(;;){
          bool ok = tag_ok(t1[0],tg) && tag_ok(t1[1],tg) && tag_ok(t1[2],tg) && tag_ok(t1[3],tg);
          if (ok) break;
          if (--bud < 0) break;
          #pragma unroll
          for (int m=0;m<4;++m){
            if (!tag_ok(t1[m],tg)){
              int id = t + m*256;
              t1[m] = ld16(&s1[(size_t)(gb0 + (id>>5))*32 + (id&31)]);
            }
          }
          drain_vm();
        }
      }
      #pragma unroll
      for (int m=0;m<4;++m){
        int id = t + m*256;
        int b = id>>5, c = id&31;
        *(ull*)(hcH + b*392 + c*4) = lo64(t1[m]);
        *(ull*)(hcL + b*392 + c*4) = hi64(t1[m]);
      }
      __syncthreads();
      // ---- MFMA-A: Wih2 x h1 (4 kt) ----
      f32x4 acc[2][2];
      #pragma unroll
      for (int bt=0;bt<2;++bt){
        #pragma unroll
        for (int ct=0;ct<2;++ct){
          f32x4 a; a[0]=biasv[ct]; a[1]=biasv[ct]; a[2]=biasv[ct]; a[3]=biasv[ct];
          acc[bt][ct]=a;
        }
      }
      #pragma unroll
      for (int kt=0;kt<4;++kt){
        short8 ah[2], al[2];
        #pragma unroll
        for (int bt=0;bt<2;++bt){
          int off = (bt*16+lr)*392 + kt*32 + lk;
          ah[bt] = *(const short8*)(hcH + off);
          al[bt] = *(const short8*)(hcL + off);
        }
        #pragma unroll
        for (int bt=0;bt<2;++bt){
          #pragma unroll
          for (int ct=0;ct<2;++ct){
            acc[bt][ct] = __builtin_amdgcn_mfma_f32_16x16x32_bf16(ah[bt], bhi[kt][ct], acc[bt][ct],0,0,0);
            acc[bt][ct] = __builtin_amdgcn_mfma_f32_16x16x32_bf16(al[bt], bhi[kt][ct], acc[bt][ct],0,0,0);
            acc[bt][ct] = __builtin_amdgcn_mfma_f32_16x16x32_bf16(ah[bt], blo[kt][ct], acc[bt][ct],0,0,0);
          }
        }
      }
      // ---- verify h2 tags (usually already valid) ----
      {
        int tg = (rr-2)&15;
        for(;;){
          bool ok = true;
          #pragma unroll
          for (int m=0;m<8;++m) ok = ok && tag_ok(t2[m],tg);
          if (ok) break;
          if (--bud < 0) break;
          #pragma unroll
          for (int m=0;m<8;++m){
            if (!tag_ok(t2[m],tg)){
              int id = t + m*256;
              t2[m] = ld16(&s2[(size_t)(gb0 + (id>>6))*64 + (id&63)]);
            }
          }
          drain_vm();
        }
      }
      // ---- stage h2, MFMA-B: Whh2 x h2 (8 kt) ----
      #pragma unroll
      for (int m=0;m<8;++m){
        int id = t + m*256;
        int b = id>>6, c = id&63;
        *(ull*)(hcH + b*392 + 128 + c*4) = lo64(t2[m]);
        *(ull*)(hcL + b*392 + 128 + c*4) = hi64(t2[m]);
      }
      __syncthreads();
      #pragma unroll
      for (int kt=4;kt<12;++kt){
        short8 ah[2], al[2];
        #pragma unroll
        for (int bt=0;bt<2;++bt){
          int off = (bt*16+lr)*392 + kt*32 + lk;
          ah[bt] = *(const short8*)(hcH + off);
          al[bt] = *(const short8*)(hcL + off);
        }
        #pragma unroll
        for (int bt=0;bt<2;++bt){
          #pragma unroll
          for (int ct=0;ct<2;++ct){
            acc[bt][ct] = __builtin_amdgcn_mfma_f32_16x16x32_bf16(ah[bt], bhi[kt][ct], acc[bt][ct],0,0,0);
            acc[bt][ct] = __builtin_amdgcn_mfma_f32_16x16x32_bf16(al[bt], bhi[kt][ct], acc[bt][ct],0,0,0);
            acc[bt][ct] = __builtin_amdgcn_mfma_f32_16x16x32_bf16(ah[bt], blo[kt][ct], acc[bt][ct],0,0,0);
          }
        }
      }
      #pragma unroll
      for (int bt=0;bt<2;++bt){
        #pragma unroll
        for (int ct=0;ct<2;++ct){
          #pragma unroll
          for (int q=0;q<4;++q)
            gl[(bt*16 + (l>>4)*4 + q)*132 + wv*32 + ct*16 + lr] = acc[bt][ct][q];
        }
      }
      __syncthreads();
      float psum = 0.f;
      ushort hb[4], lb[4];
      #pragma unroll
      for (int j=0;j<4;++j){
        f32x4 gv = *(const f32x4*)&gl[nb*132 + (lu0+j)*4];
        float ig = sigm(gv[0]), fg = sigm(gv[1]);
        float gg = tanh_(gv[2]), og = sigm(gv[3]);
        c2[j] = fg*c2[j] + ig*gg;
        float h = og*tanh_(c2[j]);
        psum += h*wo[j];
        hb[j] = f2bf(h);
        lb[j] = f2bf(h - __uint_as_float((unsigned)hb[j]<<16));
      }
      // embed tag (rr-1)&15 into lo LSBs
      {
        int tg = (rr-1)&15;
        #pragma unroll
        for (int j=0;j<4;++j)
          lb[j] = (ushort)((lb[j] & 0xFFFEu) | (uint)((tg>>j)&1));
      }
      size_t db = (size_t)((rr-1)&3)*16384 + (size_t)(gb0+nb)*64 + ((u0+lu0)>>2);
      u32x4 v0;
      v0.x = (uint)hb[0] | ((uint)hb[1]<<16); v0.y = (uint)hb[2] | ((uint)hb[3]<<16);
      v0.z = (uint)lb[0] | ((uint)lb[1]<<16); v0.w = (uint)lb[2] | ((uint)lb[3]<<16);
      st16(&h2c[db], v0);
      // publish round counter (write-safety only; NO drain)
      __syncthreads();
      if (t == 0) asti(&gf[role], rr+1);
      // output projection partial (off critical path)
      psum += __shfl_xor(psum,1,64);
      psum += __shfl_xor(psum,2,64);
      psum += __shfl_xor(psum,4,64);
      if ((t&7)==0) outp[(size_t)ts*2048 + us*256 + gb0+nb] = psum;
    }
  }
}

__global__ void k_final(const char* __restrict__ wsb, const float* __restrict__ bout,
                        float* __restrict__ out){
  const float* outp = (const float*)(wsb + OFF_OUTP);
  int id = blockIdx.x*blockDim.x + threadIdx.x;
  if (id >= B*S) return;
  int tt = id >> 8;
  int b  = id & 255;
  float s = bout[0];
  const float* p = outp + (size_t)tt*2048 + b;
  #pragma unroll
  for (int u = 0; u < 8; ++u) s += p[(size_t)u*256];
  out[(size_t)b*S + tt] = s;
}

extern "C" void kernel_launch(void* const* d_in, const int* in_sizes, int n_in,
                              void* d_out, int out_size, void* d_ws, size_t ws_size,
                              hipStream_t stream){
  const float* x    = (const float*)d_in[0];
  const float* Wih1 = (const float*)d_in[1];
  const float* Whh1 = (const float*)d_in[2];
  const float* bih1 = (const float*)d_in[3];
  const float* bhh1 = (const float*)d_in[4];
  const float* Wih2 = (const float*)d_in[5];
  const float* Whh2 = (const float*)d_in[6];
  const float* bih2 = (const float*)d_in[7];
  const float* bhh2 = (const float*)d_in[8];
  const float* Wout = (const float*)d_in[9];
  const float* bout = (const float*)d_in[10];
  char* wsb  = (char*)d_ws;
  float* out = (float*)d_out;

  (void)hipFuncSetAttribute((const void*)k_persist,
                            hipFuncAttributeMaxDynamicSharedMemorySize, DYN_LDS);

  k_zero<<<dim3(64), dim3(256), 0, stream>>>(wsb);
  k_xproj<<<dim3(B), dim3(256), 0, stream>>>(x, Wih1, bih1, bhh1, wsb);
  k_persist<<<dim3(NWG), dim3(256), DYN_LDS, stream>>>(Whh1, Wih2, Whh2, bih2, bhh2, Wout, wsb);
  k_final<<<dim3((B*S)/256), dim3(256), 0, stream>>>(wsb, bout, out);
}

// Round 17
// 1755.907 us; speedup vs baseline: 1.3134x; 1.1492x over previous
//
#include <hip/hip_runtime.h>

#define S 512
#define B 256
#define D 128
#define H1 128
#define H2 256

#define NWG 80

// byte offsets in ws
#define OFF_XPROJ 0u          // [B][512] f32 = 524288
#define OFF_H1C   524288u     // [4][B][32] 16B chunks (hi|lo interleaved) = 524288
#define OFF_H2C   1048576u    // [4][B][64] 16B chunks = 1048576
#define OFF_OUTP  2097152u    // [S][8][B] f32 = 4194304
#define OFF_FLAG  6291456u    // 8 grp * 32 int (agent scope)

#define DYN_LDS 67072

typedef unsigned long long ull;
typedef unsigned short ushort;
typedef unsigned int uint;
typedef __attribute__((ext_vector_type(8))) short short8;
typedef __attribute__((ext_vector_type(4))) float f32x4;
typedef __attribute__((ext_vector_type(4))) uint u32x4;

__device__ __forceinline__ ushort f2bf(float f){
  unsigned u = __float_as_uint(f);
  unsigned r = u + 0x7fffu + ((u>>16)&1u);
  return (ushort)(r>>16);
}
__device__ __forceinline__ float rcpf_(float x){ return __builtin_amdgcn_rcpf(x); }
__device__ __forceinline__ float sigm(float x){ return rcpf_(1.f + __expf(-x)); }
__device__ __forceinline__ float tanh_(float x){ return 1.f - 2.f*rcpf_(1.f + __expf(2.f*x)); }

__device__ __forceinline__ int aldi(const int* p){
  return __hip_atomic_load(p, __ATOMIC_RELAXED, __HIP_MEMORY_SCOPE_AGENT);
}
__device__ __forceinline__ void asti(int* p, int v){
  __hip_atomic_store(p, v, __ATOMIC_RELAXED, __HIP_MEMORY_SCOPE_AGENT);
}
// 16B uncached (L1+L2 bypass -> L3 coherence point) load/store
__device__ __forceinline__ u32x4 ld16(const u32x4* p){
  u32x4 v;
  asm volatile("global_load_dwordx4 %0, %1, off sc0 sc1"
               : "=v"(v) : "v"((ull)(size_t)p));
  return v;
}
__device__ __forceinline__ void st16(u32x4* p, u32x4 v){
  asm volatile("global_store_dwordx4 %0, %1, off sc0 sc1"
               :: "v"((ull)(size_t)p), "v"(v) : "memory");
}
__device__ __forceinline__ void drain_vm(){
  asm volatile("s_waitcnt vmcnt(0)" ::: "memory");
  __builtin_amdgcn_sched_barrier(0);
}
__device__ __forceinline__ ull lo64(u32x4 v){ return ((ull)v.y<<32) | v.x; }
__device__ __forceinline__ ull hi64(u32x4 v){ return ((ull)v.w<<32) | v.z; }

// ---------------- init kernels ----------------
__global__ void k_zero(char* wsb){
  long long id = (long long)blockIdx.x*blockDim.x + threadIdx.x;
  long long stride = (long long)gridDim.x*blockDim.x;
  ull* h = (ull*)(wsb + OFF_H1C);      // h1c + h2c contiguous = 1572864 B
  for (long long i = id; i < 196608; i += stride) h[i] = 0ull;
  ull* f = (ull*)(wsb + OFF_FLAG);
  for (long long i = id; i < 128; i += stride) f[i] = 0ull;
}

__global__ void k_xproj(const float* __restrict__ x, const float* __restrict__ Wih1,
                        const float* __restrict__ bih1, const float* __restrict__ bhh1,
                        char* __restrict__ wsb){
  __shared__ float xs[D];
  float* xproj = (float*)(wsb + OFF_XPROJ);
  int b = blockIdx.x;
  for (int d = threadIdx.x; d < D; d += blockDim.x) xs[d] = x[b*D + d];
  __syncthreads();
  for (int g = threadIdx.x; g < 4*H1; g += blockDim.x){
    float acc = bih1[g] + bhh1[g];
    const float* w = &Wih1[(size_t)g*D];
    #pragma unroll 8
    for (int d = 0; d < D; ++d) acc += xs[d]*w[d];
    xproj[(size_t)b*512 + g] = acc;
  }
}

// ---------------- persistent kernel ----------------
__global__ void __launch_bounds__(256,1)
k_persist(const float* __restrict__ Whh1,
          const float* __restrict__ Wih2, const float* __restrict__ Whh2,
          const float* __restrict__ bih2, const float* __restrict__ bhh2,
          const float* __restrict__ Wout,
          char* __restrict__ wsb){
  extern __shared__ char sm[];
  const int wg = blockIdx.x;
  const int t  = threadIdx.x;
  const int grp = wg & 7, role = wg >> 3;     // wg = role*8 + grp (XCD-local groups)
  const int gb0 = grp * 32;
  const int l = t & 63, wv = t >> 6, lr = l & 15, lk = (l >> 4) * 8;

  float* xproj = (float*)(wsb + OFF_XPROJ);
  u32x4* h1c = (u32x4*)(wsb + OFF_H1C);   // [4][B][32] chunks; 8192 chunks/buf
  u32x4* h2c = (u32x4*)(wsb + OFF_H2C);   // [4][B][64] chunks; 16384 chunks/buf
  float* outp = (float*)(wsb + OFF_OUTP);
  int* gf = (int*)(wsb + OFF_FLAG) + grp*32;

  if (role < 2){
    // ================= layer-1 WG: 64 units, 32 batches =================
    const int u0 = role * 64;
    ushort* hsH = (ushort*)sm;            // [32][136]
    ushort* hsL = (ushort*)(sm + 8704);
    float*  gl  = (float*)(sm + 17408);   // [32][260]
    short8 bhi[4][4], blo[4][4];
    #pragma unroll
    for (int kt=0;kt<4;++kt){
      #pragma unroll
      for (int ct=0;ct<4;++ct){
        int col = wv*64 + ct*16 + lr;
        int lu = col>>2, g = col&3;
        const float* src = Whh1 + (size_t)(g*H1 + u0 + lu)*D + kt*32 + lk;
        short8 vh, vl;
        #pragma unroll
        for (int j=0;j<8;++j){
          float w = src[j];
          ushort hbv = f2bf(w);
          float hf = __uint_as_float((unsigned)hbv<<16);
          vh[j] = (short)hbv; vl[j] = (short)f2bf(w - hf);
        }
        bhi[kt][ct]=vh; blo[kt][ct]=vl;
      }
    }
    f32x4 xpf[2][4];
    #pragma unroll
    for (int bt=0;bt<2;++bt){
      #pragma unroll
      for (int ct=0;ct<4;++ct){
        int col = wv*64 + ct*16 + lr;
        int lu = col>>2, g = col&3;
        #pragma unroll
        for (int q=0;q<4;++q){
          int b = gb0 + bt*16 + (l>>4)*4 + q;
          xpf[bt][ct][q] = xproj[(size_t)b*512 + g*H1 + u0 + lu];
        }
      }
    }
    const int nb = t>>3, lu0 = (t&7)*8;
    float c1[8] = {0.f,0.f,0.f,0.f,0.f,0.f,0.f,0.f};
    int lastf = (t<10) ? 0 : 0x7fffffff;
    int bud = 1<<21;

    for (int r=0; r<S; ++r){
      if (r>0){
        if (t < 64){
          int need = (t<2) ? r : (r-2);
          if (!__all((t<10) ? (lastf>=need) : true)){
            for(;;){
              if (t<10) lastf = aldi(&gf[t]);
              if (__all((t<10) ? (lastf>=need) : true)) break;
              if (--bud < 0) break;
              __builtin_amdgcn_s_sleep(1);
            }
          }
        }
        __syncthreads();
      }
      const u32x4* sB = h1c + (size_t)((r-1)&3)*8192;
      u32x4 tv[4];
      #pragma unroll
      for (int m=0;m<4;++m){
        int id = t + m*256;
        int b = id>>5, c = id&31;
        tv[m] = ld16(&sB[(size_t)(gb0+b)*32 + c]);
      }
      drain_vm();
      #pragma unroll
      for (int m=0;m<4;++m){
        int id = t + m*256;
        int b = id>>5, c = id&31;
        *(ull*)(hsH + b*136 + c*4) = lo64(tv[m]);
        *(ull*)(hsL + b*136 + c*4) = hi64(tv[m]);
      }
      __syncthreads();
      f32x4 acc[2][4];
      #pragma unroll
      for (int bt=0;bt<2;++bt){
        #pragma unroll
        for (int ct=0;ct<4;++ct) acc[bt][ct]=xpf[bt][ct];
      }
      #pragma unroll
      for (int kt=0;kt<4;++kt){
        short8 ah[2], al[2];
        #pragma unroll
        for (int bt=0;bt<2;++bt){
          int off = (bt*16+lr)*136 + kt*32 + lk;
          ah[bt] = *(const short8*)(hsH + off);
          al[bt] = *(const short8*)(hsL + off);
        }
        #pragma unroll
        for (int bt=0;bt<2;++bt){
          #pragma unroll
          for (int ct=0;ct<4;++ct){
            acc[bt][ct] = __builtin_amdgcn_mfma_f32_16x16x32_bf16(ah[bt], bhi[kt][ct], acc[bt][ct],0,0,0);
            acc[bt][ct] = __builtin_amdgcn_mfma_f32_16x16x32_bf16(al[bt], bhi[kt][ct], acc[bt][ct],0,0,0);
            acc[bt][ct] = __builtin_amdgcn_mfma_f32_16x16x32_bf16(ah[bt], blo[kt][ct], acc[bt][ct],0,0,0);
          }
        }
      }
      #pragma unroll
      for (int bt=0;bt<2;++bt){
        #pragma unroll
        for (int ct=0;ct<4;++ct){
          #pragma unroll
          for (int q=0;q<4;++q)
            gl[(bt*16 + (l>>4)*4 + q)*260 + wv*64 + ct*16 + lr] = acc[bt][ct][q];
        }
      }
      __syncthreads();
      float hv[8];
      #pragma unroll
      for (int j=0;j<8;++j){
        f32x4 gv = *(const f32x4*)&gl[nb*260 + (lu0+j)*4];
        float ig = sigm(gv[0]), fg = sigm(gv[1]);
        float gg = tanh_(gv[2]), og = sigm(gv[3]);
        c1[j] = fg*c1[j] + ig*gg;
        hv[j] = og*tanh_(c1[j]);
      }
      ushort hb[8], lb[8];
      #pragma unroll
      for (int j=0;j<8;++j){
        hb[j] = f2bf(hv[j]);
        float hf = __uint_as_float((unsigned)hb[j]<<16);
        lb[j] = f2bf(hv[j]-hf);
      }
      size_t db = (size_t)(r&3)*8192 + (size_t)(gb0+nb)*32 + ((u0+lu0)>>2);
      u32x4 v0, v1;
      v0.x = (uint)hb[0] | ((uint)hb[1]<<16); v0.y = (uint)hb[2] | ((uint)hb[3]<<16);
      v0.z = (uint)lb[0] | ((uint)lb[1]<<16); v0.w = (uint)lb[2] | ((uint)lb[3]<<16);
      v1.x = (uint)hb[4] | ((uint)hb[5]<<16); v1.y = (uint)hb[6] | ((uint)hb[7]<<16);
      v1.z = (uint)lb[4] | ((uint)lb[5]<<16); v1.w = (uint)lb[6] | ((uint)lb[7]<<16);
      st16(&h1c[db],   v0);
      st16(&h1c[db+1], v1);
      drain_vm();
      __syncthreads();
      if (t == 0) asti(&gf[role], r+1);
    }
  } else {
    // ================= layer-2 WG: 32 units, 32 batches =================
    const int us = role - 2;
    const int u0 = us * 32;
    ushort* hcH = (ushort*)sm;             // [32][392]
    ushort* hcL = (ushort*)(sm + 25088);
    float*  gl  = (float*)(sm + 50176);    // [32][132]
    short8 bhi[12][2], blo[12][2];
    #pragma unroll
    for (int kt=0;kt<12;++kt){
      #pragma unroll
      for (int ct=0;ct<2;++ct){
        int col = wv*32 + ct*16 + lr;
        int lu = col>>2, g = col&3;
        int row = g*H2 + u0 + lu;
        const float* src = (kt<4) ? (Wih2 + (size_t)row*D + kt*32 + lk)
                                  : (Whh2 + (size_t)row*H2 + (kt-4)*32 + lk);
        short8 vh, vl;
        #pragma unroll
        for (int j=0;j<8;++j){
          float w = src[j];
          ushort hbv = f2bf(w);
          float hf = __uint_as_float((unsigned)hbv<<16);
          vh[j] = (short)hbv; vl[j] = (short)f2bf(w - hf);
        }
        bhi[kt][ct]=vh; blo[kt][ct]=vl;
      }
    }
    float biasv[2];
    #pragma unroll
    for (int ct=0;ct<2;++ct){
      int col = wv*32 + ct*16 + lr;
      int lu = col>>2, g = col&3;
      biasv[ct] = bih2[g*H2+u0+lu] + bhh2[g*H2+u0+lu];
    }
    const int nb = t>>3, lu0 = (t&7)*4;
    float wo[4];
    #pragma unroll
    for (int j=0;j<4;++j) wo[j] = Wout[u0+lu0+j];
    float c2[4] = {0.f,0.f,0.f,0.f};
    int lastf = (t<10) ? 0 : 0x7fffffff;
    int bud = 1<<21;

    __syncthreads();
    if (t == 0) asti(&gf[role], 1);

    for (int rr=1; rr<=S; ++rr){
      const int ts = rr-1;
      // ---- gate on L1 flags (cached; L1 runs 2 ahead -> usually free) ----
      if (t < 64){
        if (!__all((t<2) ? (lastf>=rr) : true)){
          for(;;){
            if (t<10) lastf = aldi(&gf[t]);
            if (__all((t<2) ? (lastf>=rr) : true)) break;
            if (--bud < 0) break;
            __builtin_amdgcn_s_sleep(1);
          }
        }
      }
      __syncthreads();
      // ---- issue h1 loads immediately ----
      const u32x4* s1 = h1c + (size_t)((rr-1)&3)*8192;
      u32x4 t1[4];
      #pragma unroll
      for (int m=0;m<4;++m){
        int id = t + m*256;
        int b = id>>5, c = id&31;
        t1[m] = ld16(&s1[(size_t)(gb0+b)*32 + c]);
      }
      // ---- wave0 polls peer h2 flags while loads fly ----
      if (t < 64){
        if (!__all((t>=2 && t<10) ? (lastf>=rr) : true)){
          for(;;){
            if (t<10) lastf = aldi(&gf[t]);
            if (__all((t>=2 && t<10) ? (lastf>=rr) : true)) break;
            if (--bud < 0) break;
            __builtin_amdgcn_s_sleep(1);
          }
        }
      }
      drain_vm();
      #pragma unroll
      for (int m=0;m<4;++m){
        int id = t + m*256;
        int b = id>>5, c = id&31;
        *(ull*)(hcH + b*392 + c*4) = lo64(t1[m]);
        *(ull*)(hcL + b*392 + c*4) = hi64(t1[m]);
      }
      __syncthreads();
      // ---- issue h2 loads; latency hides under MFMA-A ----
      const u32x4* s2 = h2c + (size_t)((rr-2)&3)*16384;
      u32x4 t2[8];
      #pragma unroll
      for (int m=0;m<8;++m){
        int id = t + m*256;
        int b = id>>6, c = id&63;
        t2[m] = ld16(&s2[(size_t)(gb0+b)*64 + c]);
      }
      // ---- MFMA-A: Wih2 x h1 (4 kt) ----
      f32x4 acc[2][2];
      #pragma unroll
      for (int bt=0;bt<2;++bt){
        #pragma unroll
        for (int ct=0;ct<2;++ct){
          f32x4 a; a[0]=biasv[ct]; a[1]=biasv[ct]; a[2]=biasv[ct]; a[3]=biasv[ct];
          acc[bt][ct]=a;
        }
      }
      #pragma unroll
      for (int kt=0;kt<4;++kt){
        short8 ah[2], al[2];
        #pragma unroll
        for (int bt=0;bt<2;++bt){
          int off = (bt*16+lr)*392 + kt*32 + lk;
          ah[bt] = *(const short8*)(hcH + off);
          al[bt] = *(const short8*)(hcL + off);
        }
        #pragma unroll
        for (int bt=0;bt<2;++bt){
          #pragma unroll
          for (int ct=0;ct<2;++ct){
            acc[bt][ct] = __builtin_amdgcn_mfma_f32_16x16x32_bf16(ah[bt], bhi[kt][ct], acc[bt][ct],0,0,0);
            acc[bt][ct] = __builtin_amdgcn_mfma_f32_16x16x32_bf16(al[bt], bhi[kt][ct], acc[bt][ct],0,0,0);
            acc[bt][ct] = __builtin_amdgcn_mfma_f32_16x16x32_bf16(ah[bt], blo[kt][ct], acc[bt][ct],0,0,0);
          }
        }
      }
      // ---- stage h2, MFMA-B: Whh2 x h2 (8 kt) ----
      drain_vm();
      #pragma unroll
      for (int m=0;m<8;++m){
        int id = t + m*256;
        int b = id>>6, c = id&63;
        *(ull*)(hcH + b*392 + 128 + c*4) = lo64(t2[m]);
        *(ull*)(hcL + b*392 + 128 + c*4) = hi64(t2[m]);
      }
      __syncthreads();
      #pragma unroll
      for (int kt=4;kt<12;++kt){
        short8 ah[2], al[2];
        #pragma unroll
        for (int bt=0;bt<2;++bt){
          int off = (bt*16+lr)*392 + kt*32 + lk;
          ah[bt] = *(const short8*)(hcH + off);
          al[bt] = *(const short8*)(hcL + off);
        }
        #pragma unroll
        for (int bt=0;bt<2;++bt){
          #pragma unroll
          for (int ct=0;ct<2;++ct){
            acc[bt][ct] = __builtin_amdgcn_mfma_f32_16x16x32_bf16(ah[bt], bhi[kt][ct], acc[bt][ct],0,0,0);
            acc[bt][ct] = __builtin_amdgcn_mfma_f32_16x16x32_bf16(al[bt], bhi[kt][ct], acc[bt][ct],0,0,0);
            acc[bt][ct] = __builtin_amdgcn_mfma_f32_16x16x32_bf16(ah[bt], blo[kt][ct], acc[bt][ct],0,0,0);
          }
        }
      }
      #pragma unroll
      for (int bt=0;bt<2;++bt){
        #pragma unroll
        for (int ct=0;ct<2;++ct){
          #pragma unroll
          for (int q=0;q<4;++q)
            gl[(bt*16 + (l>>4)*4 + q)*132 + wv*32 + ct*16 + lr] = acc[bt][ct][q];
        }
      }
      __syncthreads();
      float psum = 0.f;
      ushort hb[4], lb[4];
      #pragma unroll
      for (int j=0;j<4;++j){
        f32x4 gv = *(const f32x4*)&gl[nb*132 + (lu0+j)*4];
        float ig = sigm(gv[0]), fg = sigm(gv[1]);
        float gg = tanh_(gv[2]), og = sigm(gv[3]);
        c2[j] = fg*c2[j] + ig*gg;
        float h = og*tanh_(c2[j]);
        psum += h*wo[j];
        hb[j] = f2bf(h);
        lb[j] = f2bf(h - __uint_as_float((unsigned)hb[j]<<16));
      }
      size_t db = (size_t)((rr-1)&3)*16384 + (size_t)(gb0+nb)*64 + ((u0+lu0)>>2);
      u32x4 v0;
      v0.x = (uint)hb[0] | ((uint)hb[1]<<16); v0.y = (uint)hb[2] | ((uint)hb[3]<<16);
      v0.z = (uint)lb[0] | ((uint)lb[1]<<16); v0.w = (uint)lb[2] | ((uint)lb[3]<<16);
      st16(&h2c[db], v0);
      // overlap store-ack with psum reduction + outp store
      psum += __shfl_xor(psum,1,64);
      psum += __shfl_xor(psum,2,64);
      psum += __shfl_xor(psum,4,64);
      if ((t&7)==0) outp[(size_t)ts*2048 + us*256 + gb0+nb] = psum;
      drain_vm();
      __syncthreads();
      if (t == 0) asti(&gf[role], rr+1);
    }
  }
}

__global__ void k_final(const char* __restrict__ wsb, const float* __restrict__ bout,
                        float* __restrict__ out){
  const float* outp = (const float*)(wsb + OFF_OUTP);
  int id = blockIdx.x*blockDim.x + threadIdx.x;
  if (id >= B*S) return;
  int tt = id >> 8;
  int b  = id & 255;
  float s = bout[0];
  const float* p = outp + (size_t)tt*2048 + b;
  #pragma unroll
  for (int u = 0; u < 8; ++u) s += p[(size_t)u*256];
  out[(size_t)b*S + tt] = s;
}

extern "C" void kernel_launch(void* const* d_in, const int* in_sizes, int n_in,
                              void* d_out, int out_size, void* d_ws, size_t ws_size,
                              hipStream_t stream){
  const float* x    = (const float*)d_in[0];
  const float* Wih1 = (const float*)d_in[1];
  const float* Whh1 = (const float*)d_in[2];
  const float* bih1 = (const float*)d_in[3];
  const float* bhh1 = (const float*)d_in[4];
  const float* Wih2 = (const float*)d_in[5];
  const float* Whh2 = (const float*)d_in[6];
  const float* bih2 = (const float*)d_in[7];
  const float* bhh2 = (const float*)d_in[8];
  const float* Wout = (const float*)d_in[9];
  const float* bout = (const float*)d_in[10];
  char* wsb  = (char*)d_ws;
  float* out = (float*)d_out;

  (void)hipFuncSetAttribute((const void*)k_persist,
                            hipFuncAttributeMaxDynamicSharedMemorySize, DYN_LDS);

  k_zero<<<dim3(64), dim3(256), 0, stream>>>(wsb);
  k_xproj<<<dim3(B), dim3(256), 0, stream>>>(x, Wih1, bih1, bhh1, wsb);
  k_persist<<<dim3(NWG), dim3(256), DYN_LDS, stream>>>(Whh1, Wih2, Whh2, bih2, bhh2, Wout, wsb);
  k_final<<<dim3((B*S)/256), dim3(256), 0, stream>>>(wsb, bout, out);
}